// Round 1
// baseline (948.820 us; speedup 1.0000x reference)
//
#include <hip/hip_runtime.h>

#define SEQ 2048
#define NROWS 8192            // 4 * 2048
#define NH 16
#define DHEAD 64
#define QLD 3072              // q,k,v concatenated columns

typedef float f32x4 __attribute__((ext_vector_type(4)));
typedef __bf16 bf16x8 __attribute__((ext_vector_type(8)));

__device__ __forceinline__ unsigned short f2bf(float f) {
  union { float f; unsigned u; } v; v.f = f;
  unsigned r = v.u + 0x7fffu + ((v.u >> 16) & 1u);
  return (unsigned short)(r >> 16);
}

__device__ __forceinline__ void gl16(const void* g, void* l) {
  __builtin_amdgcn_global_load_lds((const __attribute__((address_space(1))) void*)g,
                                   (__attribute__((address_space(3))) void*)l, 16, 0, 0);
}

__device__ __forceinline__ float gelu_f(float x) {
  float t = 0.7978845608028654f * (x + 0.044715f * x * x * x);
  float e = __expf(2.0f * t);
  float th = 1.0f - 2.0f / (e + 1.0f);   // tanh(t), saturates cleanly (no inf/inf)
  return 0.5f * x * (1.0f + th);
}

// ---------------- transpose + fp32->bf16 convert: Wt[n][k] = W[k][n] ----------------
__global__ __launch_bounds__(256) void transpose_cvt(const float* __restrict__ W,
                                                     unsigned short* __restrict__ Wt,
                                                     int K, int N) {
  __shared__ float tile[32][33];
  const int tx = threadIdx.x, ty = threadIdx.y;
  const int n0 = blockIdx.x * 32, k0 = blockIdx.y * 32;
#pragma unroll
  for (int i = ty; i < 32; i += 8)
    tile[i][tx] = W[(size_t)(k0 + i) * N + n0 + tx];
  __syncthreads();
#pragma unroll
  for (int i = ty; i < 32; i += 8)
    Wt[(size_t)(n0 + i) * K + k0 + tx] = f2bf(tile[tx][i]);
}

__global__ __launch_bounds__(256) void concat_bias(const float* __restrict__ bq,
                                                   const float* __restrict__ bk,
                                                   const float* __restrict__ bv,
                                                   float* __restrict__ dst) {
  int i = blockIdx.x * 256 + threadIdx.x;
  if (i < 1024) dst[i] = bq[i];
  else if (i < 2048) dst[i] = bk[i - 1024];
  else if (i < 3072) dst[i] = bv[i - 2048];
}

// ---------------- LayerNorm: fp32 in -> bf16 out, one block per 1024-row ----------------
__global__ __launch_bounds__(256) void layernorm_k(const float* __restrict__ x,
                                                   const float* __restrict__ g,
                                                   const float* __restrict__ b,
                                                   unsigned short* __restrict__ out) {
  const int row = blockIdx.x, tid = threadIdx.x;
  const float4 v = reinterpret_cast<const float4*>(x + (size_t)row * 1024)[tid];
  float s = v.x + v.y + v.z + v.w;
  float s2 = v.x * v.x + v.y * v.y + v.z * v.z + v.w * v.w;
#pragma unroll
  for (int d = 1; d < 64; d <<= 1) { s += __shfl_xor(s, d, 64); s2 += __shfl_xor(s2, d, 64); }
  __shared__ float ls[4], ls2[4];
  const int w = tid >> 6;
  if ((tid & 63) == 0) { ls[w] = s; ls2[w] = s2; }
  __syncthreads();
  s = ls[0] + ls[1] + ls[2] + ls[3];
  s2 = ls2[0] + ls2[1] + ls2[2] + ls2[3];
  const float mu = s * (1.0f / 1024.0f);
  const float var = s2 * (1.0f / 1024.0f) - mu * mu;
  const float rstd = rsqrtf(var + 1e-6f);
  const float4 gv = reinterpret_cast<const float4*>(g)[tid];
  const float4 bv = reinterpret_cast<const float4*>(b)[tid];
  ushort4 o;
  o.x = f2bf((v.x - mu) * rstd * gv.x + bv.x);
  o.y = f2bf((v.y - mu) * rstd * gv.y + bv.y);
  o.z = f2bf((v.z - mu) * rstd * gv.z + bv.z);
  o.w = f2bf((v.w - mu) * rstd * gv.w + bv.w);
  reinterpret_cast<ushort4*>(out + (size_t)row * 1024)[tid] = o;
}

// ---------------- GEMM: C[M,N] = A[M,K](bf16) * Bt[N,K]^T(bf16) + epilogue ----------------
enum { EP_BIAS = 1, EP_RES = 2, EP_GELU = 4, EP_BF16 = 8 };

template <int E>
__global__ __launch_bounds__(256, 2) void gemm_k(const unsigned short* __restrict__ A,
                                                 const unsigned short* __restrict__ Bt,
                                                 const float* __restrict__ bias,
                                                 const float* __restrict__ resid,
                                                 void* __restrict__ out,
                                                 int M, int N, int K) {
  __shared__ __align__(16) unsigned short As[2][128 * 32];
  __shared__ __align__(16) unsigned short Bs[2][128 * 32];
  const int tid = threadIdx.x;
  const int l = tid & 63, w = tid >> 6;
  const int wr = w >> 1, wc = w & 1;
  const int lr = l & 15, lg = l >> 4;
  const int bn = blockIdx.x, bm = blockIdx.y;
  const unsigned short* Ab = A + (size_t)(bm * 128) * K;
  const unsigned short* Bb = Bt + (size_t)(bn * 128) * K;
  const int srow = tid >> 2, scol = (tid & 3) * 8;

  f32x4 acc[4][4];
#pragma unroll
  for (int m = 0; m < 4; ++m)
#pragma unroll
    for (int n = 0; n < 4; ++n) acc[m][n] = 0.0f;

  const int nk = K >> 5;
  auto stage = [&](int buf, int t) {
    const unsigned short* a0 = Ab + (size_t)srow * K + t * 32 + scol;
    const unsigned short* b0 = Bb + (size_t)srow * K + t * 32 + scol;
    gl16(a0, &As[buf][tid * 8]);
    gl16(a0 + (size_t)64 * K, &As[buf][2048 + tid * 8]);
    gl16(b0, &Bs[buf][tid * 8]);
    gl16(b0 + (size_t)64 * K, &Bs[buf][2048 + tid * 8]);
  };
  stage(0, 0);
  for (int t = 0;;) {
    __syncthreads();
    if (t + 1 < nk) stage((t + 1) & 1, t + 1);
    const unsigned short* Ac = As[t & 1];
    const unsigned short* Bc = Bs[t & 1];
    bf16x8 af[4], bfr[4];
#pragma unroll
    for (int m = 0; m < 4; ++m)
      af[m] = *reinterpret_cast<const bf16x8*>(&Ac[(wr * 64 + m * 16 + lr) * 32 + lg * 8]);
#pragma unroll
    for (int n = 0; n < 4; ++n)
      bfr[n] = *reinterpret_cast<const bf16x8*>(&Bc[(wc * 64 + n * 16 + lr) * 32 + lg * 8]);
#pragma unroll
    for (int m = 0; m < 4; ++m)
#pragma unroll
      for (int n = 0; n < 4; ++n)
        acc[m][n] = __builtin_amdgcn_mfma_f32_16x16x32_bf16(af[m], bfr[n], acc[m][n], 0, 0, 0);
    if (++t == nk) break;
  }

  const int row0 = bm * 128 + wr * 64, col0 = bn * 128 + wc * 64;
#pragma unroll
  for (int m = 0; m < 4; ++m) {
#pragma unroll
    for (int n = 0; n < 4; ++n) {
      const int col = col0 + n * 16 + lr;
      float bc = 0.0f;
      if (E & EP_BIAS) bc = bias[col];
#pragma unroll
      for (int j = 0; j < 4; ++j) {
        const int row = row0 + m * 16 + lg * 4 + j;
        float v = acc[m][n][j] + bc;
        if (E & EP_RES) v += resid[(size_t)row * N + col];
        if (E & EP_GELU) v = gelu_f(v);
        if (E & EP_BF16) ((unsigned short*)out)[(size_t)row * N + col] = f2bf(v);
        else ((float*)out)[(size_t)row * N + col] = v;
      }
    }
  }
}

// ---------------- Flash attention: causal, 16 heads, Dh=64 ----------------
// qkv: [8192][3072] bf16 (q | k | v sections).  out: [8192][1024] bf16.
__global__ __launch_bounds__(256, 2) void attn_k(const unsigned short* __restrict__ qkv,
                                                 unsigned short* __restrict__ out) {
  __shared__ __align__(16) unsigned short Kl[128 * 64];   // swizzled
  __shared__ __align__(16) unsigned short Vt[64 * 136];   // transposed, +16B pad per row
  __shared__ __align__(16) unsigned short Pl[4][32 * 128]; // per-wave, swizzled
  const int tid = threadIdx.x;
  const int l = tid & 63, w = tid >> 6;
  const int lr = l & 15, lg = l >> 4;
  const int qt = blockIdx.x, bh = blockIdx.y;
  const int b = bh >> 4, h = bh & 15;
  const int q0 = qt * 128;
  const size_t rowbase = (size_t)b * SEQ;

  // Q fragments held in registers for the whole block
  bf16x8 qf[2][2];
  {
    const int qr = q0 + w * 32;
#pragma unroll
    for (int mi = 0; mi < 2; ++mi)
#pragma unroll
      for (int ks = 0; ks < 2; ++ks)
        qf[mi][ks] = *reinterpret_cast<const bf16x8*>(
            &qkv[(rowbase + qr + mi * 16 + lr) * QLD + h * 64 + ks * 32 + lg * 8]);
  }

  f32x4 oacc[2][4];
  float mrun[2][4], lrun[2][4];
#pragma unroll
  for (int mi = 0; mi < 2; ++mi) {
#pragma unroll
    for (int n = 0; n < 4; ++n) oacc[mi][n] = 0.0f;
#pragma unroll
    for (int j = 0; j < 4; ++j) { mrun[mi][j] = -1e30f; lrun[mi][j] = 0.0f; }
  }

  const int kc = (tid & 7) * 8;   // K staging: dh chunk
  const int kr0 = tid >> 3;       // K staging: row 0..31 (+p*32)
  const int vdh = (tid & 7) * 8;  // V staging: dh0
  const int vs0 = (tid >> 3) * 4; // V staging: s0 (4 rows)
  char* klb = reinterpret_cast<char*>(Kl);
  char* vtb = reinterpret_cast<char*>(Vt);

  for (int kt = 0; kt <= qt; ++kt) {
    const int kb = kt * 128;
    __syncthreads();
    // ---- stage K [128][64] with XOR swizzle ----
#pragma unroll
    for (int p = 0; p < 4; ++p) {
      const int r = kr0 + p * 32;
      uint4 d = *reinterpret_cast<const uint4*>(
          &qkv[(rowbase + kb + r) * QLD + 1024 + h * 64 + kc]);
      const int bo = (r * 128 + kc * 2) ^ ((r & 7) << 4);
      *reinterpret_cast<uint4*>(klb + bo) = d;
    }
    // ---- stage V transposed: Vt[dh][s] ----
    {
      unsigned vw[4][4];
#pragma unroll
      for (int i = 0; i < 4; ++i) {
        uint4 t = *reinterpret_cast<const uint4*>(
            &qkv[(rowbase + kb + vs0 + i) * QLD + 2048 + h * 64 + vdh]);
        vw[i][0] = t.x; vw[i][1] = t.y; vw[i][2] = t.z; vw[i][3] = t.w;
      }
#pragma unroll
      for (int jp = 0; jp < 4; ++jp) {
        unsigned e01 = (vw[0][jp] & 0xffffu) | ((vw[1][jp] & 0xffffu) << 16);
        unsigned e23 = (vw[2][jp] & 0xffffu) | ((vw[3][jp] & 0xffffu) << 16);
        unsigned o01 = (vw[0][jp] >> 16) | (vw[1][jp] & 0xffff0000u);
        unsigned o23 = (vw[2][jp] >> 16) | (vw[3][jp] & 0xffff0000u);
        const int dhE = vdh + 2 * jp;
        uint2 ev; ev.x = e01; ev.y = e23;
        uint2 ov; ov.x = o01; ov.y = o23;
        *reinterpret_cast<uint2*>(vtb + dhE * 272 + vs0 * 2) = ev;
        *reinterpret_cast<uint2*>(vtb + (dhE + 1) * 272 + vs0 * 2) = ov;
      }
    }
    __syncthreads();

    // ---- QK^T ----
    f32x4 sacc[2][8];
#pragma unroll
    for (int mi = 0; mi < 2; ++mi)
#pragma unroll
      for (int ni = 0; ni < 8; ++ni) sacc[mi][ni] = 0.0f;
#pragma unroll
    for (int ks = 0; ks < 2; ++ks) {
      bf16x8 kf[8];
#pragma unroll
      for (int ni = 0; ni < 8; ++ni) {
        const int r = ni * 16 + lr;
        const int bo = (r * 128 + (ks * 32 + lg * 8) * 2) ^ ((r & 7) << 4);
        kf[ni] = *reinterpret_cast<const bf16x8*>(klb + bo);
      }
#pragma unroll
      for (int mi = 0; mi < 2; ++mi)
#pragma unroll
        for (int ni = 0; ni < 8; ++ni)
          sacc[mi][ni] = __builtin_amdgcn_mfma_f32_16x16x32_bf16(qf[mi][ks], kf[ni], sacc[mi][ni], 0, 0, 0);
    }

    // ---- scale + causal mask ----
    const bool diag = (kt == qt);
#pragma unroll
    for (int mi = 0; mi < 2; ++mi)
#pragma unroll
      for (int ni = 0; ni < 8; ++ni)
#pragma unroll
        for (int j = 0; j < 4; ++j) {
          float v = sacc[mi][ni][j] * 0.125f;
          if (diag) {
            const int rq = q0 + w * 32 + mi * 16 + lg * 4 + j;
            const int ck = kb + ni * 16 + lr;
            if (ck > rq) v = -1e30f;
          }
          sacc[mi][ni][j] = v;
        }

    // ---- online softmax ----
#pragma unroll
    for (int mi = 0; mi < 2; ++mi) {
#pragma unroll
      for (int j = 0; j < 4; ++j) {
        float pm = sacc[mi][0][j];
#pragma unroll
        for (int ni = 1; ni < 8; ++ni) pm = fmaxf(pm, sacc[mi][ni][j]);
        pm = fmaxf(pm, __shfl_xor(pm, 1, 16));
        pm = fmaxf(pm, __shfl_xor(pm, 2, 16));
        pm = fmaxf(pm, __shfl_xor(pm, 4, 16));
        pm = fmaxf(pm, __shfl_xor(pm, 8, 16));
        const float mnew = fmaxf(mrun[mi][j], pm);
        const float alpha = __expf(mrun[mi][j] - mnew);
        mrun[mi][j] = mnew;
        float rs = 0.0f;
#pragma unroll
        for (int ni = 0; ni < 8; ++ni) {
          const float p = __expf(sacc[mi][ni][j] - mnew);
          sacc[mi][ni][j] = p;
          rs += p;
        }
        rs += __shfl_xor(rs, 1, 16);
        rs += __shfl_xor(rs, 2, 16);
        rs += __shfl_xor(rs, 4, 16);
        rs += __shfl_xor(rs, 8, 16);
        lrun[mi][j] = lrun[mi][j] * alpha + rs;
#pragma unroll
        for (int n = 0; n < 4; ++n) oacc[mi][n][j] *= alpha;
      }
    }

    // ---- P -> LDS (bf16, swizzled), wave-private ----
    char* pw = reinterpret_cast<char*>(Pl[w]);
#pragma unroll
    for (int mi = 0; mi < 2; ++mi)
#pragma unroll
      for (int ni = 0; ni < 8; ++ni)
#pragma unroll
        for (int j = 0; j < 4; ++j) {
          const int r = mi * 16 + lg * 4 + j;
          const int c = ni * 16 + lr;
          const int bo = (r * 256 + c * 2) ^ ((r & 7) << 4);
          *reinterpret_cast<unsigned short*>(pw + bo) = f2bf(sacc[mi][ni][j]);
        }
    asm volatile("" ::: "memory");  // keep ds_writes before the ds_reads below

    // ---- PV ----
    const char* pr = reinterpret_cast<const char*>(Pl[w]);
#pragma unroll
    for (int ks = 0; ks < 4; ++ks) {
      bf16x8 pf[2], vf[4];
#pragma unroll
      for (int mi = 0; mi < 2; ++mi) {
        const int r = mi * 16 + lr;
        const int bo = (r * 256 + (ks * 32 + lg * 8) * 2) ^ ((r & 7) << 4);
        pf[mi] = *reinterpret_cast<const bf16x8*>(pr + bo);
      }
#pragma unroll
      for (int n = 0; n < 4; ++n) {
        const int r = n * 16 + lr;
        vf[n] = *reinterpret_cast<const bf16x8*>(vtb + (r * 272 + (ks * 32 + lg * 8) * 2));
      }
#pragma unroll
      for (int mi = 0; mi < 2; ++mi)
#pragma unroll
        for (int n = 0; n < 4; ++n)
          oacc[mi][n] = __builtin_amdgcn_mfma_f32_16x16x32_bf16(pf[mi], vf[n], oacc[mi][n], 0, 0, 0);
    }
  }

  // ---- finalize: divide by l, store bf16 ----
#pragma unroll
  for (int mi = 0; mi < 2; ++mi)
#pragma unroll
    for (int j = 0; j < 4; ++j) {
      const float inv = 1.0f / lrun[mi][j];
      const size_t row = rowbase + q0 + w * 32 + mi * 16 + lg * 4 + j;
#pragma unroll
      for (int n = 0; n < 4; ++n)
        out[row * 1024 + h * 64 + n * 16 + lr] = f2bf(oacc[mi][n][j] * inv);
    }
}

// ---------------- host ----------------
extern "C" void kernel_launch(void* const* d_in, const int* in_sizes, int n_in,
                              void* d_out, int out_size, void* d_ws, size_t ws_size,
                              hipStream_t stream) {
  const float* x   = (const float*)d_in[0];
  const float* Wq  = (const float*)d_in[1];
  const float* bq  = (const float*)d_in[2];
  const float* Wk  = (const float*)d_in[3];
  const float* bk  = (const float*)d_in[4];
  const float* Wv  = (const float*)d_in[5];
  const float* bv  = (const float*)d_in[6];
  const float* Wo  = (const float*)d_in[7];
  const float* W1  = (const float*)d_in[8];
  const float* b1  = (const float*)d_in[9];
  const float* W2  = (const float*)d_in[10];
  const float* b2  = (const float*)d_in[11];
  const float* g1  = (const float*)d_in[12];
  const float* be1 = (const float*)d_in[13];
  const float* g2  = (const float*)d_in[14];
  const float* be2 = (const float*)d_in[15];

  char* ws = (char*)d_ws;
  size_t off = 0;
  auto alloc = [&](size_t bytes) { char* p = ws + off; off += (bytes + 255) & ~(size_t)255; return p; };
  unsigned short* WqkvT = (unsigned short*)alloc((size_t)3072 * 1024 * 2);
  unsigned short* WoT   = (unsigned short*)alloc((size_t)1024 * 1024 * 2);
  unsigned short* W1T   = (unsigned short*)alloc((size_t)4096 * 1024 * 2);
  unsigned short* W2T   = (unsigned short*)alloc((size_t)1024 * 4096 * 2);
  float*          bqkv  = (float*)alloc((size_t)3072 * 4);
  unsigned short* normed = (unsigned short*)alloc((size_t)NROWS * 1024 * 2);  // LN1 & LN2 output
  unsigned short* qkvbuf = (unsigned short*)alloc((size_t)NROWS * 4096 * 2);  // qkv (3072 cols); reused as FF hidden (4096 cols)
  unsigned short* attnb  = (unsigned short*)alloc((size_t)NROWS * 1024 * 2);
  float*          x1     = (float*)alloc((size_t)NROWS * 1024 * 4);

  const dim3 tb(32, 8);
  transpose_cvt<<<dim3(32, 32), tb, 0, stream>>>(Wq, WqkvT, 1024, 1024);
  transpose_cvt<<<dim3(32, 32), tb, 0, stream>>>(Wk, WqkvT + 1024 * 1024, 1024, 1024);
  transpose_cvt<<<dim3(32, 32), tb, 0, stream>>>(Wv, WqkvT + 2 * 1024 * 1024, 1024, 1024);
  transpose_cvt<<<dim3(32, 32), tb, 0, stream>>>(Wo, WoT, 1024, 1024);
  transpose_cvt<<<dim3(128, 32), tb, 0, stream>>>(W1, W1T, 1024, 4096);
  transpose_cvt<<<dim3(32, 128), tb, 0, stream>>>(W2, W2T, 4096, 1024);
  concat_bias<<<12, 256, 0, stream>>>(bq, bk, bv, bqkv);

  layernorm_k<<<NROWS, 256, 0, stream>>>(x, g1, be1, normed);
  gemm_k<(EP_BIAS | EP_BF16)><<<dim3(24, 64), 256, 0, stream>>>(normed, WqkvT, bqkv, nullptr, qkvbuf, NROWS, 3072, 1024);
  attn_k<<<dim3(16, 64), 256, 0, stream>>>(qkvbuf, attnb);
  gemm_k<EP_RES><<<dim3(8, 64), 256, 0, stream>>>(attnb, WoT, nullptr, x, x1, NROWS, 1024, 1024);
  layernorm_k<<<NROWS, 256, 0, stream>>>(x1, g2, be2, normed);
  gemm_k<(EP_BIAS | EP_GELU | EP_BF16)><<<dim3(32, 64), 256, 0, stream>>>(normed, W1T, b1, nullptr, qkvbuf, NROWS, 4096, 1024);
  gemm_k<(EP_BIAS | EP_RES)><<<dim3(8, 64), 256, 0, stream>>>(qkvbuf, W2T, b2, x1, d_out, NROWS, 1024, 4096);
}

// Round 2
// 553.189 us; speedup vs baseline: 1.7152x; 1.7152x over previous
//
#include <hip/hip_runtime.h>

#define SEQ 2048
#define NROWS 8192            // 4 * 2048
#define NH 16
#define DHEAD 64
#define QLD 3072              // q,k,v concatenated columns

typedef float f32x4 __attribute__((ext_vector_type(4)));
typedef __bf16 bf16x8 __attribute__((ext_vector_type(8)));

__device__ __forceinline__ unsigned short f2bf(float f) {
  union { float f; unsigned u; } v; v.f = f;
  unsigned r = v.u + 0x7fffu + ((v.u >> 16) & 1u);
  return (unsigned short)(r >> 16);
}

__device__ __forceinline__ void gl16(const void* g, void* l) {
  __builtin_amdgcn_global_load_lds((const __attribute__((address_space(1))) void*)g,
                                   (__attribute__((address_space(3))) void*)l, 16, 0, 0);
}

__device__ __forceinline__ float gelu_f(float x) {
  float t = 0.7978845608028654f * (x + 0.044715f * x * x * x);
  float e = __expf(2.0f * t);
  float th = 1.0f - 2.0f / (e + 1.0f);   // tanh(t), saturates cleanly (no inf/inf)
  return 0.5f * x * (1.0f + th);
}

// cvt_pk_bf16_f32: no builtin on gfx950 — inline asm (RNE)
#define CVTPK(dst, lo, hi) asm("v_cvt_pk_bf16_f32 %0, %1, %2" : "=v"(dst) : "v"(lo), "v"(hi))

#if __has_builtin(__builtin_amdgcn_permlane32_swap)
#define P32SWAP(a, b, x, y) { auto _t = __builtin_amdgcn_permlane32_swap((a), (b), false, false); (x) = _t[0]; (y) = _t[1]; }
#else
#define P32SWAP(a, b, x, y) { unsigned _as = (unsigned)__shfl_xor((int)(a), 32, 64); \
  unsigned _bs = (unsigned)__shfl_xor((int)(b), 32, 64); \
  (x) = (l < 32) ? (a) : _bs; (y) = (l < 32) ? _as : (b); }
#endif
#if __has_builtin(__builtin_amdgcn_permlane16_swap)
#define P16SWAP(a, b, x, y) { auto _t = __builtin_amdgcn_permlane16_swap((a), (b), false, false); (x) = _t[0]; (y) = _t[1]; }
#else
#define P16SWAP(a, b, x, y) { unsigned _as = (unsigned)__shfl_xor((int)(a), 16, 64); \
  unsigned _bs = (unsigned)__shfl_xor((int)(b), 16, 64); \
  (x) = (l & 16) ? _bs : (a); (y) = (l & 16) ? (b) : _as; }
#endif

// ---------------- transpose + fp32->bf16 convert: Wt[n][k] = W[k][n] ----------------
__global__ __launch_bounds__(256) void transpose_cvt(const float* __restrict__ W,
                                                     unsigned short* __restrict__ Wt,
                                                     int K, int N) {
  __shared__ float tile[32][33];
  const int tx = threadIdx.x, ty = threadIdx.y;
  const int n0 = blockIdx.x * 32, k0 = blockIdx.y * 32;
#pragma unroll
  for (int i = ty; i < 32; i += 8)
    tile[i][tx] = W[(size_t)(k0 + i) * N + n0 + tx];
  __syncthreads();
#pragma unroll
  for (int i = ty; i < 32; i += 8)
    Wt[(size_t)(n0 + i) * K + k0 + tx] = f2bf(tile[tx][i]);
}

__global__ __launch_bounds__(256) void concat_bias(const float* __restrict__ bq,
                                                   const float* __restrict__ bk,
                                                   const float* __restrict__ bv,
                                                   float* __restrict__ dst) {
  int i = blockIdx.x * 256 + threadIdx.x;
  if (i < 1024) dst[i] = bq[i];
  else if (i < 2048) dst[i] = bk[i - 1024];
  else if (i < 3072) dst[i] = bv[i - 2048];
}

// ---------------- LayerNorm: fp32 in -> bf16 out, one block per 1024-row ----------------
__global__ __launch_bounds__(256) void layernorm_k(const float* __restrict__ x,
                                                   const float* __restrict__ g,
                                                   const float* __restrict__ b,
                                                   unsigned short* __restrict__ out) {
  const int row = blockIdx.x, tid = threadIdx.x;
  const float4 v = reinterpret_cast<const float4*>(x + (size_t)row * 1024)[tid];
  float s = v.x + v.y + v.z + v.w;
  float s2 = v.x * v.x + v.y * v.y + v.z * v.z + v.w * v.w;
#pragma unroll
  for (int d = 1; d < 64; d <<= 1) { s += __shfl_xor(s, d, 64); s2 += __shfl_xor(s2, d, 64); }
  __shared__ float ls[4], ls2[4];
  const int w = tid >> 6;
  if ((tid & 63) == 0) { ls[w] = s; ls2[w] = s2; }
  __syncthreads();
  s = ls[0] + ls[1] + ls[2] + ls[3];
  s2 = ls2[0] + ls2[1] + ls2[2] + ls2[3];
  const float mu = s * (1.0f / 1024.0f);
  const float var = s2 * (1.0f / 1024.0f) - mu * mu;
  const float rstd = rsqrtf(var + 1e-6f);
  const float4 gv = reinterpret_cast<const float4*>(g)[tid];
  const float4 bv = reinterpret_cast<const float4*>(b)[tid];
  ushort4 o;
  o.x = f2bf((v.x - mu) * rstd * gv.x + bv.x);
  o.y = f2bf((v.y - mu) * rstd * gv.y + bv.y);
  o.z = f2bf((v.z - mu) * rstd * gv.z + bv.z);
  o.w = f2bf((v.w - mu) * rstd * gv.w + bv.w);
  reinterpret_cast<ushort4*>(out + (size_t)row * 1024)[tid] = o;
}

// ---------------- GEMM: C[M,N] = A[M,K](bf16) * Bt[N,K]^T(bf16) + epilogue ----------------
enum { EP_BIAS = 1, EP_RES = 2, EP_GELU = 4, EP_BF16 = 8, EP_QSCALE = 16 };

template <int E>
__global__ __launch_bounds__(256, 2) void gemm_k(const unsigned short* __restrict__ A,
                                                 const unsigned short* __restrict__ Bt,
                                                 const float* __restrict__ bias,
                                                 const float* __restrict__ resid,
                                                 void* __restrict__ out,
                                                 int M, int N, int K) {
  __shared__ __align__(16) unsigned short As[2][128 * 32];
  __shared__ __align__(16) unsigned short Bs[2][128 * 32];
  const int tid = threadIdx.x;
  const int l = tid & 63, w = tid >> 6;
  const int wr = w >> 1, wc = w & 1;
  const int lr = l & 15, lg = l >> 4;
  const int bn = blockIdx.x, bm = blockIdx.y;
  const unsigned short* Ab = A + (size_t)(bm * 128) * K;
  const unsigned short* Bb = Bt + (size_t)(bn * 128) * K;
  const int srow = tid >> 2, scol = (tid & 3) * 8;

  f32x4 acc[4][4];
#pragma unroll
  for (int m = 0; m < 4; ++m)
#pragma unroll
    for (int n = 0; n < 4; ++n) acc[m][n] = 0.0f;

  const int nk = K >> 5;
  auto stage = [&](int buf, int t) {
    const unsigned short* a0 = Ab + (size_t)srow * K + t * 32 + scol;
    const unsigned short* b0 = Bb + (size_t)srow * K + t * 32 + scol;
    gl16(a0, &As[buf][tid * 8]);
    gl16(a0 + (size_t)64 * K, &As[buf][2048 + tid * 8]);
    gl16(b0, &Bs[buf][tid * 8]);
    gl16(b0 + (size_t)64 * K, &Bs[buf][2048 + tid * 8]);
  };
  stage(0, 0);
  for (int t = 0;;) {
    __syncthreads();
    if (t + 1 < nk) stage((t + 1) & 1, t + 1);
    const unsigned short* Ac = As[t & 1];
    const unsigned short* Bc = Bs[t & 1];
    bf16x8 af[4], bfr[4];
#pragma unroll
    for (int m = 0; m < 4; ++m)
      af[m] = *reinterpret_cast<const bf16x8*>(&Ac[(wr * 64 + m * 16 + lr) * 32 + lg * 8]);
#pragma unroll
    for (int n = 0; n < 4; ++n)
      bfr[n] = *reinterpret_cast<const bf16x8*>(&Bc[(wc * 64 + n * 16 + lr) * 32 + lg * 8]);
#pragma unroll
    for (int m = 0; m < 4; ++m)
#pragma unroll
      for (int n = 0; n < 4; ++n)
        acc[m][n] = __builtin_amdgcn_mfma_f32_16x16x32_bf16(af[m], bfr[n], acc[m][n], 0, 0, 0);
    if (++t == nk) break;
  }

  const int row0 = bm * 128 + wr * 64, col0 = bn * 128 + wc * 64;
#pragma unroll
  for (int m = 0; m < 4; ++m) {
#pragma unroll
    for (int n = 0; n < 4; ++n) {
      const int col = col0 + n * 16 + lr;
      float bc = 0.0f;
      if (E & EP_BIAS) bc = bias[col];
#pragma unroll
      for (int j = 0; j < 4; ++j) {
        const int row = row0 + m * 16 + lg * 4 + j;
        float v = acc[m][n][j] + bc;
        if (E & EP_RES) v += resid[(size_t)row * N + col];
        if (E & EP_GELU) v = gelu_f(v);
        if (E & EP_QSCALE) { if (col < 1024) v *= 0.125f; }   // pre-scale Q by 1/sqrt(Dh)
        if (E & EP_BF16) ((unsigned short*)out)[(size_t)row * N + col] = f2bf(v);
        else ((float*)out)[(size_t)row * N + col] = v;
      }
    }
  }
}

// ---------------- Flash attention: causal, 16 heads, Dh=64 ----------------
// Swapped-operand scheme: S^T = mfma(K, Q) so each lane owns one q-row's k-strip.
// In-register softmax (2 shfl_xor) and in-register P->B-frag via cvt_pk + permlane swaps.
// O^T = mfma(V^T, P^T). 512 threads, q-tile 128 (16 rows/wave), KV-tile 64,
// pair (qt, 15-qt) for exact load balance: every block does 34 k-tile iterations.
__global__ __launch_bounds__(512, 4) void attn_k(const unsigned short* __restrict__ qkv,
                                                 unsigned short* __restrict__ out) {
  __shared__ __align__(16) unsigned short Kl[2][4096];  // [64 rows][128B], XOR-swizzled
  __shared__ __align__(16) unsigned short Vt[2][4096];  // V^T [64 dh][128B], XOR-swizzled
  const int tid = threadIdx.x;
  const int l = tid & 63, w = tid >> 6;
  const int lr = l & 15, lg = l >> 4;
  const int bh = blockIdx.y;
  const int b = bh >> 4, h = bh & 15;
  const size_t rowbase = (size_t)b * SEQ;
  char* klb = (char*)Kl;
  char* vtb = (char*)Vt;
  const int sg = tid & 15, dhg = tid >> 4;  // V staging roles (tid < 256)

  // K tile: 8 chunks of 1KB, wave w stages chunk w via global_load_lds with
  // inverse-swizzled per-lane SOURCE (LDS dest stays linear = swizzled content).
  auto stageK = [&](int buf, int kb2) {
    const int r = (w << 3) + (l >> 3);
    const char* src = (const char*)(qkv + (rowbase + kb2 + r) * QLD + 1024 + h * 64)
                      + 16 * ((l & 7) ^ (l >> 3));
    gl16(src, klb + buf * 8192 + (w << 10) + (l << 4));
  };
  auto loadV = [&](int kb2, uint2* vr) {
    if (tid < 256) {
#pragma unroll
      for (int i = 0; i < 4; ++i)
        vr[i] = *reinterpret_cast<const uint2*>(
            qkv + (rowbase + kb2 + sg * 4 + i) * QLD + 2048 + h * 64 + dhg * 4);
    }
  };
  auto writeV = [&](int buf, const uint2* vr) {
    if (tid < 256) {
      char* vb = vtb + buf * 8192;
#pragma unroll
      for (int jj = 0; jj < 4; ++jj) {
        const int dh = dhg * 4 + jj;
        unsigned a0 = (jj < 2) ? vr[0].x : vr[0].y;
        unsigned a1 = (jj < 2) ? vr[1].x : vr[1].y;
        unsigned a2 = (jj < 2) ? vr[2].x : vr[2].y;
        unsigned a3 = (jj < 2) ? vr[3].x : vr[3].y;
        unsigned s01, s23;
        if (jj & 1) {
          s01 = (a0 >> 16) | (a1 & 0xffff0000u);
          s23 = (a2 >> 16) | (a3 & 0xffff0000u);
        } else {
          s01 = (a0 & 0xffffu) | (a1 << 16);
          s23 = (a2 & 0xffffu) | (a3 << 16);
        }
        const int bo = (dh * 128 + sg * 8) ^ ((dh & 7) << 4);
        uint2 p; p.x = s01; p.y = s23;
        *reinterpret_cast<uint2*>(vb + bo) = p;
      }
    }
  };

#pragma unroll 1
  for (int seg = 0; seg < 2; ++seg) {
    const int qt = seg ? (15 - blockIdx.x) : blockIdx.x;
    const int q0 = qt << 7;
    const int ktmax = 2 * qt + 1;
    const int qwmin = q0 + w * 16;
    const int qrow = qwmin + lr;

    bf16x8 qf[2];
#pragma unroll
    for (int ks = 0; ks < 2; ++ks)
      qf[ks] = *reinterpret_cast<const bf16x8*>(
          qkv + (rowbase + qrow) * QLD + h * 64 + ks * 32 + lg * 8);

    f32x4 oacc[4];
#pragma unroll
    for (int n = 0; n < 4; ++n) oacc[n] = 0.0f;
    float mrun = -1e30f, lrun = 0.0f;

    {  // prologue: stage kt=0 into buffer 0
      stageK(0, 0);
      uint2 vr[4];
      loadV(0, vr);
      writeV(0, vr);
    }
    __syncthreads();

#pragma unroll 1
    for (int kt = 0; kt <= ktmax; ++kt) {
      const int cur = kt & 1, nb = cur ^ 1;
      const int kb = kt << 6;
      const bool more = kt < ktmax;
      const bool active = kb <= qwmin + 15;  // wave-uniform: skip fully-masked tiles
      uint2 vr[4];
      if (more) { stageK(nb, (kt + 1) << 6); loadV((kt + 1) << 6, vr); }

      f32x4 sacc[4];
      if (active) {
        // ---- S^T = K * Q^T : lane owns q-row (lr), k = ni*16 + lg*4 + j ----
#pragma unroll
        for (int ni = 0; ni < 4; ++ni) sacc[ni] = 0.0f;
        const char* kc = klb + cur * 8192;
        __builtin_amdgcn_s_setprio(1);
#pragma unroll
        for (int ks = 0; ks < 2; ++ks) {
#pragma unroll
          for (int ni = 0; ni < 4; ++ni) {
            const int r = ni * 16 + lr;
            const int bo = (r * 128 + ks * 64 + lg * 16) ^ ((lr & 7) << 4);
            bf16x8 kf = *reinterpret_cast<const bf16x8*>(kc + bo);
            sacc[ni] = __builtin_amdgcn_mfma_f32_16x16x32_bf16(kf, qf[ks], sacc[ni], 0, 0, 0);
          }
        }
        __builtin_amdgcn_s_setprio(0);

        // ---- causal mask (Q already pre-scaled by 0.125) ----
        if (kb + 63 > qwmin) {
#pragma unroll
          for (int ni = 0; ni < 4; ++ni)
#pragma unroll
            for (int j = 0; j < 4; ++j)
              if (kb + ni * 16 + lg * 4 + j > qrow) sacc[ni][j] = -1e30f;
        }

        // ---- online softmax: lane-local + 2 shuffles ----
        float pm = sacc[0][0];
#pragma unroll
        for (int ni = 0; ni < 4; ++ni)
#pragma unroll
          for (int j = 0; j < 4; ++j) pm = fmaxf(pm, sacc[ni][j]);
        pm = fmaxf(pm, __shfl_xor(pm, 16, 64));
        pm = fmaxf(pm, __shfl_xor(pm, 32, 64));
        const float mnew = fmaxf(mrun, pm);
        const float alpha = __expf(mrun - mnew);
        mrun = mnew;
        float rs = 0.0f;
#pragma unroll
        for (int ni = 0; ni < 4; ++ni)
#pragma unroll
          for (int j = 0; j < 4; ++j) {
            const float p = __expf(sacc[ni][j] - mnew);
            sacc[ni][j] = p;
            rs += p;
          }
        rs += __shfl_xor(rs, 16, 64);
        rs += __shfl_xor(rs, 32, 64);
        lrun = lrun * alpha + rs;
#pragma unroll
        for (int n = 0; n < 4; ++n) oacc[n] *= alpha;
      }

      if (more) writeV(nb, vr);  // overlapped: HBM latency hid under QK+softmax

      if (active) {
        // ---- O^T += V^T * P^T : build B-frags in-register ----
        const char* vc = vtb + cur * 8192;
#pragma unroll
        for (int ks2 = 0; ks2 < 2; ++ks2) {
          unsigned U0, U1, U2, U3, C0, C1, W0, W1, W2, W3;
          CVTPK(U0, sacc[2 * ks2][0], sacc[2 * ks2][1]);
          CVTPK(U1, sacc[2 * ks2][2], sacc[2 * ks2][3]);
          CVTPK(U2, sacc[2 * ks2 + 1][0], sacc[2 * ks2 + 1][1]);
          CVTPK(U3, sacc[2 * ks2 + 1][2], sacc[2 * ks2 + 1][3]);
          P32SWAP(U0, U2, C0, C1);
          P16SWAP(C0, C1, W0, W2);
          P32SWAP(U1, U3, C0, C1);
          P16SWAP(C0, C1, W1, W3);
          union { uint4 u; bf16x8 v; } pu;
          pu.u = make_uint4(W0, W1, W2, W3);
          __builtin_amdgcn_s_setprio(1);
#pragma unroll
          for (int n = 0; n < 4; ++n) {
            const int r = n * 16 + lr;
            const int bo = (r * 128 + ks2 * 64 + lg * 16) ^ ((lr & 7) << 4);
            bf16x8 vf = *reinterpret_cast<const bf16x8*>(vc + bo);
            oacc[n] = __builtin_amdgcn_mfma_f32_16x16x32_bf16(vf, pu.v, oacc[n], 0, 0, 0);
          }
          __builtin_amdgcn_s_setprio(0);
        }
      }
      __syncthreads();
    }

    // ---- finalize: O^T lane holds q=lr, dh = n*16 + lg*4 + j ----
    const float inv = 1.0f / lrun;
#pragma unroll
    for (int n = 0; n < 4; ++n) {
      ushort4 o;
      o.x = f2bf(oacc[n][0] * inv);
      o.y = f2bf(oacc[n][1] * inv);
      o.z = f2bf(oacc[n][2] * inv);
      o.w = f2bf(oacc[n][3] * inv);
      *reinterpret_cast<ushort4*>(out + (rowbase + qrow) * 1024 + h * 64 + n * 16 + lg * 4) = o;
    }
  }
}

// ---------------- host ----------------
extern "C" void kernel_launch(void* const* d_in, const int* in_sizes, int n_in,
                              void* d_out, int out_size, void* d_ws, size_t ws_size,
                              hipStream_t stream) {
  const float* x   = (const float*)d_in[0];
  const float* Wq  = (const float*)d_in[1];
  const float* bq  = (const float*)d_in[2];
  const float* Wk  = (const float*)d_in[3];
  const float* bk  = (const float*)d_in[4];
  const float* Wv  = (const float*)d_in[5];
  const float* bv  = (const float*)d_in[6];
  const float* Wo  = (const float*)d_in[7];
  const float* W1  = (const float*)d_in[8];
  const float* b1  = (const float*)d_in[9];
  const float* W2  = (const float*)d_in[10];
  const float* b2  = (const float*)d_in[11];
  const float* g1  = (const float*)d_in[12];
  const float* be1 = (const float*)d_in[13];
  const float* g2  = (const float*)d_in[14];
  const float* be2 = (const float*)d_in[15];

  char* ws = (char*)d_ws;
  size_t off = 0;
  auto alloc = [&](size_t bytes) { char* p = ws + off; off += (bytes + 255) & ~(size_t)255; return p; };
  unsigned short* WqkvT = (unsigned short*)alloc((size_t)3072 * 1024 * 2);
  unsigned short* WoT   = (unsigned short*)alloc((size_t)1024 * 1024 * 2);
  unsigned short* W1T   = (unsigned short*)alloc((size_t)4096 * 1024 * 2);
  unsigned short* W2T   = (unsigned short*)alloc((size_t)1024 * 4096 * 2);
  float*          bqkv  = (float*)alloc((size_t)3072 * 4);
  unsigned short* normed = (unsigned short*)alloc((size_t)NROWS * 1024 * 2);
  unsigned short* qkvbuf = (unsigned short*)alloc((size_t)NROWS * 4096 * 2);
  unsigned short* attnb  = (unsigned short*)alloc((size_t)NROWS * 1024 * 2);
  float*          x1     = (float*)alloc((size_t)NROWS * 1024 * 4);

  const dim3 tb(32, 8);
  transpose_cvt<<<dim3(32, 32), tb, 0, stream>>>(Wq, WqkvT, 1024, 1024);
  transpose_cvt<<<dim3(32, 32), tb, 0, stream>>>(Wk, WqkvT + 1024 * 1024, 1024, 1024);
  transpose_cvt<<<dim3(32, 32), tb, 0, stream>>>(Wv, WqkvT + 2 * 1024 * 1024, 1024, 1024);
  transpose_cvt<<<dim3(32, 32), tb, 0, stream>>>(Wo, WoT, 1024, 1024);
  transpose_cvt<<<dim3(128, 32), tb, 0, stream>>>(W1, W1T, 1024, 4096);
  transpose_cvt<<<dim3(32, 128), tb, 0, stream>>>(W2, W2T, 4096, 1024);
  concat_bias<<<12, 256, 0, stream>>>(bq, bk, bv, bqkv);

  layernorm_k<<<NROWS, 256, 0, stream>>>(x, g1, be1, normed);
  gemm_k<(EP_BIAS | EP_BF16 | EP_QSCALE)><<<dim3(24, 64), 256, 0, stream>>>(normed, WqkvT, bqkv, nullptr, qkvbuf, NROWS, 3072, 1024);
  attn_k<<<dim3(8, 64), 512, 0, stream>>>(qkvbuf, attnb);
  gemm_k<EP_RES><<<dim3(8, 64), 256, 0, stream>>>(attnb, WoT, nullptr, x, x1, NROWS, 1024, 1024);
  layernorm_k<<<NROWS, 256, 0, stream>>>(x1, g2, be2, normed);
  gemm_k<(EP_BIAS | EP_GELU | EP_BF16)><<<dim3(32, 64), 256, 0, stream>>>(normed, W1T, b1, nullptr, qkvbuf, NROWS, 4096, 1024);
  gemm_k<(EP_BIAS | EP_RES)><<<dim3(8, 64), 256, 0, stream>>>(qkvbuf, W2T, b2, x1, d_out, NROWS, 1024, 4096);
}

// Round 3
// 535.639 us; speedup vs baseline: 1.7714x; 1.0328x over previous
//
#include <hip/hip_runtime.h>

#define SEQ 2048
#define NROWS 8192            // 4 * 2048
#define NH 16
#define DHEAD 64
#define QLD 3072              // q,k,v concatenated columns

typedef float f32x4 __attribute__((ext_vector_type(4)));
typedef __bf16 bf16x8 __attribute__((ext_vector_type(8)));

__device__ __forceinline__ unsigned short f2bf(float f) {
  union { float f; unsigned u; } v; v.f = f;
  unsigned r = v.u + 0x7fffu + ((v.u >> 16) & 1u);
  return (unsigned short)(r >> 16);
}

__device__ __forceinline__ void gl16(const void* g, void* l) {
  __builtin_amdgcn_global_load_lds((const __attribute__((address_space(1))) void*)g,
                                   (__attribute__((address_space(3))) void*)l, 16, 0, 0);
}

__device__ __forceinline__ float gelu_f(float x) {
  float t = 0.7978845608028654f * (x + 0.044715f * x * x * x);
  float e = __expf(2.0f * t);
  float th = 1.0f - 2.0f / (e + 1.0f);   // tanh(t), saturates cleanly (no inf/inf)
  return 0.5f * x * (1.0f + th);
}

#define CVTPK(dst, lo, hi) asm("v_cvt_pk_bf16_f32 %0, %1, %2" : "=v"(dst) : "v"(lo), "v"(hi))

#if __has_builtin(__builtin_amdgcn_permlane32_swap)
#define P32SWAP(a, b, x, y) { auto _t = __builtin_amdgcn_permlane32_swap((a), (b), false, false); (x) = _t[0]; (y) = _t[1]; }
#else
#define P32SWAP(a, b, x, y) { unsigned _as = (unsigned)__shfl_xor((int)(a), 32, 64); \
  unsigned _bs = (unsigned)__shfl_xor((int)(b), 32, 64); \
  (x) = (l < 32) ? (a) : _bs; (y) = (l < 32) ? _as : (b); }
#endif
#if __has_builtin(__builtin_amdgcn_permlane16_swap)
#define P16SWAP(a, b, x, y) { auto _t = __builtin_amdgcn_permlane16_swap((a), (b), false, false); (x) = _t[0]; (y) = _t[1]; }
#else
#define P16SWAP(a, b, x, y) { unsigned _as = (unsigned)__shfl_xor((int)(a), 16, 64); \
  unsigned _bs = (unsigned)__shfl_xor((int)(b), 16, 64); \
  (x) = (l & 16) ? _bs : (a); (y) = (l & 16) ? (b) : _as; }
#endif

#define MEMFENCE asm volatile("" ::: "memory")
#define BAR() do { MEMFENCE; __builtin_amdgcn_s_barrier(); MEMFENCE; } while (0)
#define WAIT_LGKM0 asm volatile("s_waitcnt lgkmcnt(0)" ::: "memory")
#define WAIT_VM0 asm volatile("s_waitcnt vmcnt(0)" ::: "memory")

// ---------------- transpose + fp32->bf16 convert: Wt[n][k] = W[k][n] ----------------
__global__ __launch_bounds__(256) void transpose_cvt(const float* __restrict__ W,
                                                     unsigned short* __restrict__ Wt,
                                                     int K, int N) {
  __shared__ float tile[32][33];
  const int tx = threadIdx.x, ty = threadIdx.y;
  const int n0 = blockIdx.x * 32, k0 = blockIdx.y * 32;
#pragma unroll
  for (int i = ty; i < 32; i += 8)
    tile[i][tx] = W[(size_t)(k0 + i) * N + n0 + tx];
  __syncthreads();
#pragma unroll
  for (int i = ty; i < 32; i += 8)
    Wt[(size_t)(n0 + i) * K + k0 + tx] = f2bf(tile[tx][i]);
}

__global__ __launch_bounds__(256) void concat_bias(const float* __restrict__ bq,
                                                   const float* __restrict__ bk,
                                                   const float* __restrict__ bv,
                                                   float* __restrict__ dst) {
  int i = blockIdx.x * 256 + threadIdx.x;
  if (i < 1024) dst[i] = bq[i];
  else if (i < 2048) dst[i] = bk[i - 1024];
  else if (i < 3072) dst[i] = bv[i - 2048];
}

// ---------------- LayerNorm: fp32 in -> bf16 out, one block per 1024-row ----------------
__global__ __launch_bounds__(256) void layernorm_k(const float* __restrict__ x,
                                                   const float* __restrict__ g,
                                                   const float* __restrict__ b,
                                                   unsigned short* __restrict__ out) {
  const int row = blockIdx.x, tid = threadIdx.x;
  const float4 v = reinterpret_cast<const float4*>(x + (size_t)row * 1024)[tid];
  float s = v.x + v.y + v.z + v.w;
  float s2 = v.x * v.x + v.y * v.y + v.z * v.z + v.w * v.w;
#pragma unroll
  for (int d = 1; d < 64; d <<= 1) { s += __shfl_xor(s, d, 64); s2 += __shfl_xor(s2, d, 64); }
  __shared__ float ls[4], ls2[4];
  const int w = tid >> 6;
  if ((tid & 63) == 0) { ls[w] = s; ls2[w] = s2; }
  __syncthreads();
  s = ls[0] + ls[1] + ls[2] + ls[3];
  s2 = ls2[0] + ls2[1] + ls2[2] + ls2[3];
  const float mu = s * (1.0f / 1024.0f);
  const float var = s2 * (1.0f / 1024.0f) - mu * mu;
  const float rstd = rsqrtf(var + 1e-6f);
  const float4 gv = reinterpret_cast<const float4*>(g)[tid];
  const float4 bv = reinterpret_cast<const float4*>(b)[tid];
  ushort4 o;
  o.x = f2bf((v.x - mu) * rstd * gv.x + bv.x);
  o.y = f2bf((v.y - mu) * rstd * gv.y + bv.y);
  o.z = f2bf((v.z - mu) * rstd * gv.z + bv.z);
  o.w = f2bf((v.w - mu) * rstd * gv.w + bv.w);
  reinterpret_cast<ushort4*>(out + (size_t)row * 1024)[tid] = o;
}

enum { EP_BIAS = 1, EP_RES = 2, EP_GELU = 4, EP_BF16 = 8, EP_QSCALE = 16 };

// ---------------- Phase-pipelined GEMM: C[M,N] = A[M,K] * Bt[N,K]^T + epilogue ----------
// BM=256, BK=64, 512 threads (8 waves). BN=256: waves 2Mx4N (wave-tile 128x64).
// BN=128: waves 4Mx2N (wave-tile 64x64). LDS rows 128B, XOR-swizzled (T2) via
// pre-swizzled global_load_lds source. 4 phases/K-tile, single vmcnt(0) drain at
// phase 3 (T3/T4-lite), raw barriers, setprio around MFMA (T5), XCD swizzle (T1).
template <int BN, int E>
__global__ __launch_bounds__(512, 2) void gemm8_k(const unsigned short* __restrict__ A,
                                                  const unsigned short* __restrict__ Bt,
                                                  const float* __restrict__ bias,
                                                  const float* __restrict__ resid,
                                                  void* __restrict__ out,
                                                  int M, int N, int K) {
  constexpr int BM = 256;
  constexpr int NWC = (BN == 256) ? 4 : 2;   // waves along N
  constexpr int WM = (BN == 256) ? 128 : 64; // wave-tile M
  constexpr int MI = WM / 16;                // 8 or 4 m-frags
  constexpr int MQ = MI / 2;                 // m-frags per phase-half
  __shared__ __align__(16) unsigned short As[2][BM * 64];
  __shared__ __align__(16) unsigned short Bs[2][BN * 64];

  const int tid = threadIdx.x;
  const int l = tid & 63, w = tid >> 6;
  const int lr = l & 15, lg = l >> 4;
  const int wr = w / NWC, wc = w % NWC;

  // T1: bijective XCD swizzle (nwg % 8 == 0 for all our grids)
  const int gx = gridDim.x;
  const int nwg = gx * gridDim.y;
  int lin = blockIdx.y * gx + blockIdx.x;
  lin = (lin & 7) * (nwg >> 3) + (lin >> 3);
  const int bn = lin % gx, bm = lin / gx;

  const unsigned short* Ab = A + (size_t)(bm * BM) * K;
  const unsigned short* Bb = Bt + (size_t)(bn * BN) * K;

  // staging: seg = 8 rows x 128B = 1KB; lane l writes bytes [l*16, l*16+16).
  // content swizzle: store-slot s holds logical slot s ^ (row&7).
  const int srow = l >> 3;
  const int sslot = (l & 7) ^ (srow & 7);
  auto stA = [&](int buf, int t, int seg) {
    gl16((const char*)(Ab + (size_t)(seg * 8 + srow) * K + t * 64) + sslot * 16,
         (char*)As[buf] + seg * 1024 + l * 16);
  };
  auto stB = [&](int buf, int t, int seg) {
    gl16((const char*)(Bb + (size_t)(seg * 8 + srow) * K + t * 64) + sslot * 16,
         (char*)Bs[buf] + seg * 1024 + l * 16);
  };
  auto stage = [&](int buf, int t, int p) {
    if (BN == 256) {
      if (p == 0)      { stA(buf, t, w); stA(buf, t, 8 + w);  stB(buf, t, w); }
      else if (p == 1) { stA(buf, t, 16 + w); stA(buf, t, 24 + w); stB(buf, t, 8 + w); }
      else if (p == 2) { stB(buf, t, 16 + w); stB(buf, t, 24 + w); }
    } else {
      if (p == 0)      { stA(buf, t, w); stB(buf, t, w); }
      else if (p == 1) { stA(buf, t, 8 + w); stB(buf, t, 8 + w); }
      else if (p == 2) { stA(buf, t, 16 + w); stA(buf, t, 24 + w); }
    }
  };
  // swizzled fragment read: logical (row r, 16B-slot j) at byte r*128 + (j^(r&7))*16
  auto rdA = [&](int buf, int r, int ks) {
    return *reinterpret_cast<const bf16x8*>(
        (const char*)As[buf] + r * 128 + (((ks << 2) + lg) ^ (r & 7)) * 16);
  };
  auto rdB = [&](int buf, int r, int ks) {
    return *reinterpret_cast<const bf16x8*>(
        (const char*)Bs[buf] + r * 128 + (((ks << 2) + lg) ^ (r & 7)) * 16);
  };

  f32x4 acc[MI][4];
#pragma unroll
  for (int m = 0; m < MI; ++m)
#pragma unroll
    for (int n = 0; n < 4; ++n) acc[m][n] = 0.0f;

  const int NK = K >> 6;
  // prologue: stage tile 0 fully, drain, barrier
#pragma unroll
  for (int p = 0; p < 3; ++p) stage(0, 0, p);
  WAIT_VM0;
  BAR();

#pragma unroll 2
  for (int kt = 0; kt < NK; ++kt) {
    const int c = kt & 1, nb = c ^ 1;
    const bool more = kt + 1 < NK;
    bf16x8 a0[MQ][2], a1[MQ][2], b0[2][2], b1[2][2];

    // ---- phase 0: read A-half0 + B-half0; prefetch p0 ----
#pragma unroll
    for (int mi = 0; mi < MQ; ++mi)
#pragma unroll
      for (int ks = 0; ks < 2; ++ks) a0[mi][ks] = rdA(c, wr * WM + mi * 16 + lr, ks);
#pragma unroll
    for (int ni = 0; ni < 2; ++ni)
#pragma unroll
      for (int ks = 0; ks < 2; ++ks) b0[ni][ks] = rdB(c, wc * 64 + ni * 16 + lr, ks);
    if (more) stage(nb, kt + 1, 0);
    BAR();
    WAIT_LGKM0;
    __builtin_amdgcn_s_setprio(1);
#pragma unroll
    for (int mi = 0; mi < MQ; ++mi)
#pragma unroll
      for (int ni = 0; ni < 2; ++ni)
#pragma unroll
        for (int ks = 0; ks < 2; ++ks)
          acc[mi][ni] = __builtin_amdgcn_mfma_f32_16x16x32_bf16(a0[mi][ks], b0[ni][ks], acc[mi][ni], 0, 0, 0);
    __builtin_amdgcn_s_setprio(0);
    BAR();

    // ---- phase 1: read B-half1; prefetch p1 ----
#pragma unroll
    for (int ni = 0; ni < 2; ++ni)
#pragma unroll
      for (int ks = 0; ks < 2; ++ks) b1[ni][ks] = rdB(c, wc * 64 + (2 + ni) * 16 + lr, ks);
    if (more) stage(nb, kt + 1, 1);
    BAR();
    WAIT_LGKM0;
    __builtin_amdgcn_s_setprio(1);
#pragma unroll
    for (int mi = 0; mi < MQ; ++mi)
#pragma unroll
      for (int ni = 0; ni < 2; ++ni)
#pragma unroll
        for (int ks = 0; ks < 2; ++ks)
          acc[mi][2 + ni] = __builtin_amdgcn_mfma_f32_16x16x32_bf16(a0[mi][ks], b1[ni][ks], acc[mi][2 + ni], 0, 0, 0);
    __builtin_amdgcn_s_setprio(0);
    BAR();

    // ---- phase 2: read A-half1; prefetch p2 ----
#pragma unroll
    for (int mi = 0; mi < MQ; ++mi)
#pragma unroll
      for (int ks = 0; ks < 2; ++ks) a1[mi][ks] = rdA(c, wr * WM + (MQ + mi) * 16 + lr, ks);
    if (more) stage(nb, kt + 1, 2);
    BAR();
    WAIT_LGKM0;
    __builtin_amdgcn_s_setprio(1);
#pragma unroll
    for (int mi = 0; mi < MQ; ++mi)
#pragma unroll
      for (int ni = 0; ni < 2; ++ni)
#pragma unroll
        for (int ks = 0; ks < 2; ++ks)
          acc[MQ + mi][ni] = __builtin_amdgcn_mfma_f32_16x16x32_bf16(a1[mi][ks], b0[ni][ks], acc[MQ + mi][ni], 0, 0, 0);
    __builtin_amdgcn_s_setprio(0);
    BAR();

    // ---- phase 3: no reads; drain prefetch, trailing barrier ----
    __builtin_amdgcn_s_setprio(1);
#pragma unroll
    for (int mi = 0; mi < MQ; ++mi)
#pragma unroll
      for (int ni = 0; ni < 2; ++ni)
#pragma unroll
        for (int ks = 0; ks < 2; ++ks)
          acc[MQ + mi][2 + ni] = __builtin_amdgcn_mfma_f32_16x16x32_bf16(a1[mi][ks], b1[ni][ks], acc[MQ + mi][2 + ni], 0, 0, 0);
    __builtin_amdgcn_s_setprio(0);
    WAIT_VM0;
    BAR();
  }

  // ---- epilogue ----
  const int row0 = bm * BM + wr * WM;
  const int col0 = bn * BN + wc * 64;
#pragma unroll
  for (int m = 0; m < MI; ++m) {
#pragma unroll
    for (int n = 0; n < 4; ++n) {
      const int col = col0 + n * 16 + lr;
      float bc = 0.0f;
      if (E & EP_BIAS) bc = bias[col];
#pragma unroll
      for (int j = 0; j < 4; ++j) {
        const int row = row0 + m * 16 + lg * 4 + j;
        float v = acc[m][n][j] + bc;
        if (E & EP_RES) v += resid[(size_t)row * N + col];
        if (E & EP_GELU) v = gelu_f(v);
        if (E & EP_QSCALE) { if (col < 1024) v *= 0.125f; }
        if (E & EP_BF16) ((unsigned short*)out)[(size_t)row * N + col] = f2bf(v);
        else ((float*)out)[(size_t)row * N + col] = v;
      }
    }
  }
}

// ---------------- Flash attention: causal, 16 heads, Dh=64 (unchanged from R2) ----------
__global__ __launch_bounds__(512, 4) void attn_k(const unsigned short* __restrict__ qkv,
                                                 unsigned short* __restrict__ out) {
  __shared__ __align__(16) unsigned short Kl[2][4096];
  __shared__ __align__(16) unsigned short Vt[2][4096];
  const int tid = threadIdx.x;
  const int l = tid & 63, w = tid >> 6;
  const int lr = l & 15, lg = l >> 4;
  const int bh = blockIdx.y;
  const int b = bh >> 4, h = bh & 15;
  const size_t rowbase = (size_t)b * SEQ;
  char* klb = (char*)Kl;
  char* vtb = (char*)Vt;
  const int sg = tid & 15, dhg = tid >> 4;

  auto stageK = [&](int buf, int kb2) {
    const int r = (w << 3) + (l >> 3);
    const char* src = (const char*)(qkv + (rowbase + kb2 + r) * QLD + 1024 + h * 64)
                      + 16 * ((l & 7) ^ (l >> 3));
    gl16(src, klb + buf * 8192 + (w << 10) + (l << 4));
  };
  auto loadV = [&](int kb2, uint2* vr) {
    if (tid < 256) {
#pragma unroll
      for (int i = 0; i < 4; ++i)
        vr[i] = *reinterpret_cast<const uint2*>(
            qkv + (rowbase + kb2 + sg * 4 + i) * QLD + 2048 + h * 64 + dhg * 4);
    }
  };
  auto writeV = [&](int buf, const uint2* vr) {
    if (tid < 256) {
      char* vb = vtb + buf * 8192;
#pragma unroll
      for (int jj = 0; jj < 4; ++jj) {
        const int dh = dhg * 4 + jj;
        unsigned a0 = (jj < 2) ? vr[0].x : vr[0].y;
        unsigned a1 = (jj < 2) ? vr[1].x : vr[1].y;
        unsigned a2 = (jj < 2) ? vr[2].x : vr[2].y;
        unsigned a3 = (jj < 2) ? vr[3].x : vr[3].y;
        unsigned s01, s23;
        if (jj & 1) {
          s01 = (a0 >> 16) | (a1 & 0xffff0000u);
          s23 = (a2 >> 16) | (a3 & 0xffff0000u);
        } else {
          s01 = (a0 & 0xffffu) | (a1 << 16);
          s23 = (a2 & 0xffffu) | (a3 << 16);
        }
        const int bo = (dh * 128 + sg * 8) ^ ((dh & 7) << 4);
        uint2 p; p.x = s01; p.y = s23;
        *reinterpret_cast<uint2*>(vb + bo) = p;
      }
    }
  };

#pragma unroll 1
  for (int seg = 0; seg < 2; ++seg) {
    const int qt = seg ? (15 - blockIdx.x) : blockIdx.x;
    const int q0 = qt << 7;
    const int ktmax = 2 * qt + 1;
    const int qwmin = q0 + w * 16;
    const int qrow = qwmin + lr;

    bf16x8 qf[2];
#pragma unroll
    for (int ks = 0; ks < 2; ++ks)
      qf[ks] = *reinterpret_cast<const bf16x8*>(
          qkv + (rowbase + qrow) * QLD + h * 64 + ks * 32 + lg * 8);

    f32x4 oacc[4];
#pragma unroll
    for (int n = 0; n < 4; ++n) oacc[n] = 0.0f;
    float mrun = -1e30f, lrun = 0.0f;

    {
      stageK(0, 0);
      uint2 vr[4];
      loadV(0, vr);
      writeV(0, vr);
    }
    __syncthreads();

#pragma unroll 1
    for (int kt = 0; kt <= ktmax; ++kt) {
      const int cur = kt & 1, nb = cur ^ 1;
      const int kb = kt << 6;
      const bool more = kt < ktmax;
      const bool active = kb <= qwmin + 15;
      uint2 vr[4];
      if (more) { stageK(nb, (kt + 1) << 6); loadV((kt + 1) << 6, vr); }

      f32x4 sacc[4];
      if (active) {
#pragma unroll
        for (int ni = 0; ni < 4; ++ni) sacc[ni] = 0.0f;
        const char* kc = klb + cur * 8192;
        __builtin_amdgcn_s_setprio(1);
#pragma unroll
        for (int ks = 0; ks < 2; ++ks) {
#pragma unroll
          for (int ni = 0; ni < 4; ++ni) {
            const int r = ni * 16 + lr;
            const int bo = (r * 128 + ks * 64 + lg * 16) ^ ((lr & 7) << 4);
            bf16x8 kf = *reinterpret_cast<const bf16x8*>(kc + bo);
            sacc[ni] = __builtin_amdgcn_mfma_f32_16x16x32_bf16(kf, qf[ks], sacc[ni], 0, 0, 0);
          }
        }
        __builtin_amdgcn_s_setprio(0);

        if (kb + 63 > qwmin) {
#pragma unroll
          for (int ni = 0; ni < 4; ++ni)
#pragma unroll
            for (int j = 0; j < 4; ++j)
              if (kb + ni * 16 + lg * 4 + j > qrow) sacc[ni][j] = -1e30f;
        }

        float pm = sacc[0][0];
#pragma unroll
        for (int ni = 0; ni < 4; ++ni)
#pragma unroll
          for (int j = 0; j < 4; ++j) pm = fmaxf(pm, sacc[ni][j]);
        pm = fmaxf(pm, __shfl_xor(pm, 16, 64));
        pm = fmaxf(pm, __shfl_xor(pm, 32, 64));
        const float mnew = fmaxf(mrun, pm);
        const float alpha = __expf(mrun - mnew);
        mrun = mnew;
        float rs = 0.0f;
#pragma unroll
        for (int ni = 0; ni < 4; ++ni)
#pragma unroll
          for (int j = 0; j < 4; ++j) {
            const float p = __expf(sacc[ni][j] - mnew);
            sacc[ni][j] = p;
            rs += p;
          }
        rs += __shfl_xor(rs, 16, 64);
        rs += __shfl_xor(rs, 32, 64);
        lrun = lrun * alpha + rs;
#pragma unroll
        for (int n = 0; n < 4; ++n) oacc[n] *= alpha;
      }

      if (more) writeV(nb, vr);

      if (active) {
        const char* vc = vtb + cur * 8192;
#pragma unroll
        for (int ks2 = 0; ks2 < 2; ++ks2) {
          unsigned U0, U1, U2, U3, C0, C1, W0, W1, W2, W3;
          CVTPK(U0, sacc[2 * ks2][0], sacc[2 * ks2][1]);
          CVTPK(U1, sacc[2 * ks2][2], sacc[2 * ks2][3]);
          CVTPK(U2, sacc[2 * ks2 + 1][0], sacc[2 * ks2 + 1][1]);
          CVTPK(U3, sacc[2 * ks2 + 1][2], sacc[2 * ks2 + 1][3]);
          P32SWAP(U0, U2, C0, C1);
          P16SWAP(C0, C1, W0, W2);
          P32SWAP(U1, U3, C0, C1);
          P16SWAP(C0, C1, W1, W3);
          union { uint4 u; bf16x8 v; } pu;
          pu.u = make_uint4(W0, W1, W2, W3);
          __builtin_amdgcn_s_setprio(1);
#pragma unroll
          for (int n = 0; n < 4; ++n) {
            const int r = n * 16 + lr;
            const int bo = (r * 128 + ks2 * 64 + lg * 16) ^ ((lr & 7) << 4);
            bf16x8 vf = *reinterpret_cast<const bf16x8*>(vc + bo);
            oacc[n] = __builtin_amdgcn_mfma_f32_16x16x32_bf16(vf, pu.v, oacc[n], 0, 0, 0);
          }
          __builtin_amdgcn_s_setprio(0);
        }
      }
      __syncthreads();
    }

    const float inv = 1.0f / lrun;
#pragma unroll
    for (int n = 0; n < 4; ++n) {
      ushort4 o;
      o.x = f2bf(oacc[n][0] * inv);
      o.y = f2bf(oacc[n][1] * inv);
      o.z = f2bf(oacc[n][2] * inv);
      o.w = f2bf(oacc[n][3] * inv);
      *reinterpret_cast<ushort4*>(out + (rowbase + qrow) * 1024 + h * 64 + n * 16 + lg * 4) = o;
    }
  }
}

// ---------------- host ----------------
extern "C" void kernel_launch(void* const* d_in, const int* in_sizes, int n_in,
                              void* d_out, int out_size, void* d_ws, size_t ws_size,
                              hipStream_t stream) {
  const float* x   = (const float*)d_in[0];
  const float* Wq  = (const float*)d_in[1];
  const float* bq  = (const float*)d_in[2];
  const float* Wk  = (const float*)d_in[3];
  const float* bk  = (const float*)d_in[4];
  const float* Wv  = (const float*)d_in[5];
  const float* bv  = (const float*)d_in[6];
  const float* Wo  = (const float*)d_in[7];
  const float* W1  = (const float*)d_in[8];
  const float* b1  = (const float*)d_in[9];
  const float* W2  = (const float*)d_in[10];
  const float* b2  = (const float*)d_in[11];
  const float* g1  = (const float*)d_in[12];
  const float* be1 = (const float*)d_in[13];
  const float* g2  = (const float*)d_in[14];
  const float* be2 = (const float*)d_in[15];

  char* ws = (char*)d_ws;
  size_t off = 0;
  auto alloc = [&](size_t bytes) { char* p = ws + off; off += (bytes + 255) & ~(size_t)255; return p; };
  unsigned short* WqkvT = (unsigned short*)alloc((size_t)3072 * 1024 * 2);
  unsigned short* WoT   = (unsigned short*)alloc((size_t)1024 * 1024 * 2);
  unsigned short* W1T   = (unsigned short*)alloc((size_t)4096 * 1024 * 2);
  unsigned short* W2T   = (unsigned short*)alloc((size_t)1024 * 4096 * 2);
  float*          bqkv  = (float*)alloc((size_t)3072 * 4);
  unsigned short* normed = (unsigned short*)alloc((size_t)NROWS * 1024 * 2);
  unsigned short* qkvbuf = (unsigned short*)alloc((size_t)NROWS * 4096 * 2);
  unsigned short* attnb  = (unsigned short*)alloc((size_t)NROWS * 1024 * 2);
  float*          x1     = (float*)alloc((size_t)NROWS * 1024 * 4);

  const dim3 tb(32, 8);
  transpose_cvt<<<dim3(32, 32), tb, 0, stream>>>(Wq, WqkvT, 1024, 1024);
  transpose_cvt<<<dim3(32, 32), tb, 0, stream>>>(Wk, WqkvT + 1024 * 1024, 1024, 1024);
  transpose_cvt<<<dim3(32, 32), tb, 0, stream>>>(Wv, WqkvT + 2 * 1024 * 1024, 1024, 1024);
  transpose_cvt<<<dim3(32, 32), tb, 0, stream>>>(Wo, WoT, 1024, 1024);
  transpose_cvt<<<dim3(128, 32), tb, 0, stream>>>(W1, W1T, 1024, 4096);
  transpose_cvt<<<dim3(32, 128), tb, 0, stream>>>(W2, W2T, 4096, 1024);
  concat_bias<<<12, 256, 0, stream>>>(bq, bk, bv, bqkv);

  layernorm_k<<<NROWS, 256, 0, stream>>>(x, g1, be1, normed);
  gemm8_k<256, (EP_BIAS | EP_BF16 | EP_QSCALE)><<<dim3(12, 32), 512, 0, stream>>>(normed, WqkvT, bqkv, nullptr, qkvbuf, NROWS, 3072, 1024);
  attn_k<<<dim3(8, 64), 512, 0, stream>>>(qkvbuf, attnb);
  gemm8_k<128, EP_RES><<<dim3(8, 32), 512, 0, stream>>>(attnb, WoT, nullptr, x, x1, NROWS, 1024, 1024);
  layernorm_k<<<NROWS, 256, 0, stream>>>(x1, g2, be2, normed);
  gemm8_k<256, (EP_BIAS | EP_GELU | EP_BF16)><<<dim3(16, 32), 512, 0, stream>>>(normed, W1T, b1, nullptr, qkvbuf, NROWS, 4096, 1024);
  gemm8_k<128, (EP_BIAS | EP_RES)><<<dim3(8, 32), 512, 0, stream>>>(qkvbuf, W2T, b2, x1, d_out, NROWS, 1024, 4096);
}